// Round 5
// baseline (316.069 us; speedup 1.0000x reference)
//
#include <hip/hip_runtime.h>
#include <cstdint>
#include <cstddef>

#define HH 256
#define WW 256
#define HWW (HH * WW)

typedef __attribute__((ext_vector_type(8))) short bf16x8;
typedef __attribute__((ext_vector_type(4))) float f32x4;

__device__ inline unsigned short f2bf(float f) {
  unsigned u = __float_as_uint(f);
  unsigned r = (u + 0x7fffu + ((u >> 16) & 1u)) >> 16;
  return (unsigned short)r;
}
__device__ inline float bf2f(unsigned short u) {
  return __uint_as_float((unsigned)u << 16);
}
__device__ inline float bf_lo(unsigned w) { return __uint_as_float(w << 16); }
__device__ inline float bf_hi(unsigned w) { return __uint_as_float(w & 0xffff0000u); }

// ---------------------------------------------------------------------------
// Weight repack.
// mode 0: [cin][9] fp32 (cout==1 gate conv)
// mode 1: [k][cin][cout] fp32 (deform)
// mode 2: MFMA A-fragment pack (weights = A operand), bf16:
//   dst[((ot*NST+s)*64+l)*8+j]: o = ot*16+(l&15); klin = s*32+(l>>4)*8+j;
//   tap=klin/cin, c=klin%cin; val = (tap<9 && o<cout) ? W[o][c][tap] : 0
// ---------------------------------------------------------------------------
struct RD { const float* src; void* dst; int cin, cout, mode; };
struct RA { RD d[9]; };

__global__ __launch_bounds__(256) void repack_k(RA a) {
  const RD t = a.d[blockIdx.x];
  if (t.mode == 2) {
    const int NST = (t.cin * 9 + 31) / 32;
    const int OT = (t.cout + 15) / 16;
    const int n = OT * NST * 512;
    unsigned short* dst = (unsigned short*)t.dst;
    for (int i = threadIdx.x; i < n; i += 256) {
      int j = i & 7;
      int l = (i >> 3) & 63;
      int rest = i >> 9;
      int s = rest % NST;
      int ot = rest / NST;
      int o = ot * 16 + (l & 15);
      int klin = s * 32 + ((l >> 4) << 3) + j;
      int tap = klin / t.cin;
      int c = klin % t.cin;
      float v = 0.f;
      if (tap < 9 && o < t.cout) v = t.src[(o * t.cin + c) * 9 + tap];
      dst[i] = f2bf(v);
    }
  } else {
    float* dst = (float*)t.dst;
    const int n = t.cin * t.cout * 9;
    for (int i = threadIdx.x; i < n; i += 256) {
      int k = i % 9;
      int rest = i / 9;
      int c = rest % t.cin;
      int o = rest / t.cin;
      if (t.mode == 0) dst[(c * 9 + k) * t.cout + o] = t.src[(o * t.cin + c) * 9 + k];
      else             dst[(k * t.cin + c) * t.cout + o] = t.src[(o * t.cin + c) * 9 + k];
    }
  }
}

// ---------------------------------------------------------------------------
// f_E, f_F (fp32 NCHW) -> bf16 NHWC [B][H][W][16].
// ---------------------------------------------------------------------------
__global__ __launch_bounds__(256) void nhwc2_k(
    const float* __restrict__ fe, const float* __restrict__ ff,
    unsigned short* __restrict__ xe, unsigned short* __restrict__ xf) {
  const int b = blockIdx.z;
  const int pixel = blockIdx.x * 256 + threadIdx.x;
#pragma unroll
  for (int t = 0; t < 2; ++t) {
    const float* src = t ? ff : fe;
    unsigned short* dst = t ? xf : xe;
    unsigned w[8];
#pragma unroll
    for (int j = 0; j < 8; ++j) {
      unsigned short lo = f2bf(src[((size_t)b * 16 + 2 * j) * HWW + pixel]);
      unsigned short hi = f2bf(src[((size_t)b * 16 + 2 * j + 1) * HWW + pixel]);
      w[j] = (unsigned)lo | ((unsigned)hi << 16);
    }
    uint4* d4 = (uint4*)(dst + ((size_t)b * HWW + pixel) * 16);
    d4[0] = make_uint4(w[0], w[1], w[2], w[3]);
    d4[1] = make_uint4(w[4], w[5], w[6], w[7]);
  }
}

// ---------------------------------------------------------------------------
// Generic single-conv (K5, K8, K9). Same structure as round 4.
// ---------------------------------------------------------------------------
template <int NSLOT, int OT, int OUT_MODE, int COUTR>
__global__ __launch_bounds__(256) void conv_nhwc(
    const unsigned short* __restrict__ inA, const unsigned short* __restrict__ inB,
    const unsigned short* __restrict__ wtm, const float* __restrict__ bias,
    void* __restrict__ outv) {
  constexpr int CIN = NSLOT * 8;
  constexpr int NST = (CIN * 9 + 31) / 32;
  constexpr int SHIFT = (NSLOT == 4) ? 1 : 2;
  constexpr int STRIDE = NSLOT * 16;
  constexpr int PX = 66, PY = 10;
  __shared__ __align__(16) char smem[PY * PX * STRIDE];

  const int b = blockIdx.z;
  const int tx0 = blockIdx.x * 64;
  const int ty0 = blockIdx.y * 8;
  const int tid = threadIdx.x;
  const int lane = tid & 63;
  const int wv = tid >> 6;

  bf16x8 afr[OT][NST];
#pragma unroll
  for (int ot = 0; ot < OT; ++ot)
#pragma unroll
    for (int s = 0; s < NST; ++s)
      afr[ot][s] = *(const bf16x8*)(wtm + (size_t)(((ot * NST + s) * 64 + lane) * 8));

  const int px_l = lane & 15;
  const int og = lane >> 4;

  f32x4 acc[8][OT];
#pragma unroll
  for (int ot = 0; ot < OT; ++ot) {
    f32x4 bv;
#pragma unroll
    for (int r = 0; r < 4; ++r) {
      int o = ot * 16 + og * 4 + r;
      bv[r] = bias[o < COUTR ? o : COUTR - 1];
    }
#pragma unroll
    for (int t = 0; t < 8; ++t) acc[t][ot] = bv;
  }

  for (int i = tid; i < PY * PX * NSLOT; i += 256) {
    int pp = i / NSLOT;
    int s = i - pp * NSLOT;
    int ly = pp / PX;
    int lx = pp - ly * PX;
    int gy = ty0 + ly - 1;
    int gx = tx0 + lx - 1;
    uint4 v = make_uint4(0, 0, 0, 0);
    if (gy >= 0 && gy < HH && gx >= 0 && gx < WW) {
      const unsigned short* src = (NSLOT == 2 || s < 2) ? inA : inB;
      int sl = (NSLOT == 4 && s >= 2) ? s - 2 : s;
      v = *(const uint4*)(src + ((size_t)b * HWW + (size_t)gy * WW + gx) * 16 + sl * 8);
    }
    int swz = (s ^ (pp >> SHIFT)) & (NSLOT - 1);
    *(uint4*)(smem + (size_t)pp * STRIDE + (swz << 4)) = v;
  }
  __syncthreads();

  int dpix[NST], dslot[NST];
#pragma unroll
  for (int s = 0; s < NST; ++s) {
    int klin = s * 32 + og * 8;
    int tap = klin / CIN;
    if (tap > 8) tap = 8;
    int coff = klin % CIN;
    dpix[s] = (tap / 3) * PX + (tap % 3);
    dslot[s] = coff >> 3;
  }

  const int oy_l = wv * 2;
#pragma unroll
  for (int t = 0; t < 8; ++t) {
    const int base_pix = (oy_l + (t >> 2)) * PX + (t & 3) * 16 + px_l;
#pragma unroll
    for (int s = 0; s < NST; ++s) {
      int pp = base_pix + dpix[s];
      int off = pp * STRIDE + (((dslot[s] ^ (pp >> SHIFT)) & (NSLOT - 1)) << 4);
      bf16x8 bvv = *(const bf16x8*)(smem + off);
#pragma unroll
      for (int ot = 0; ot < OT; ++ot)
        acc[t][ot] = __builtin_amdgcn_mfma_f32_16x16x32_bf16(afr[ot][s], bvv, acc[t][ot], 0, 0, 0);
    }
  }

#pragma unroll
  for (int t = 0; t < 8; ++t) {
    const int gy = ty0 + oy_l + (t >> 2);
    const int gx = tx0 + (t & 3) * 16 + px_l;
#pragma unroll
    for (int ot = 0; ot < OT; ++ot) {
      const int o0 = ot * 16 + og * 4;
      if (OUT_MODE == 2) {
        unsigned lo = (unsigned)f2bf(fmaxf(acc[t][ot][0], 0.f)) |
                      ((unsigned)f2bf(fmaxf(acc[t][ot][1], 0.f)) << 16);
        unsigned hi = (unsigned)f2bf(fmaxf(acc[t][ot][2], 0.f)) |
                      ((unsigned)f2bf(fmaxf(acc[t][ot][3], 0.f)) << 16);
        uint2* dst = (uint2*)((unsigned short*)outv +
                              ((size_t)b * HWW + (size_t)gy * WW + gx) * 16 + o0);
        *dst = make_uint2(lo, hi);
      } else {
#pragma unroll
        for (int r = 0; r < 4; ++r) {
          int o = o0 + r;
          if (o < COUTR)
            ((float*)outv)[((size_t)b * COUTR + o) * HWW + (size_t)gy * WW + gx] =
                fmaxf(acc[t][ot][r], 0.f);
        }
      }
    }
  }
}

// ---------------------------------------------------------------------------
// Fused K1+K4: two CIN=32 convs over the SAME staged input cat(XE,XF).
// Both outputs bf16 NHWC + ReLU.
// ---------------------------------------------------------------------------
__global__ __launch_bounds__(256) void conv_dual_k(
    const unsigned short* __restrict__ inA, const unsigned short* __restrict__ inB,
    const unsigned short* __restrict__ w1, const float* __restrict__ b1,
    const unsigned short* __restrict__ w2, const float* __restrict__ b2,
    unsigned short* __restrict__ out1, unsigned short* __restrict__ out2) {
  constexpr int NSLOT = 4, NST = 9, SHIFT = 1, STRIDE = 64, PX = 66, PY = 10;
  __shared__ __align__(16) char smem[PY * PX * STRIDE];

  const int b = blockIdx.z;
  const int tx0 = blockIdx.x * 64;
  const int ty0 = blockIdx.y * 8;
  const int tid = threadIdx.x;
  const int lane = tid & 63;
  const int wv = tid >> 6;

  bf16x8 afr1[NST], afr2[NST];
#pragma unroll
  for (int s = 0; s < NST; ++s) {
    afr1[s] = *(const bf16x8*)(w1 + (size_t)((s * 64 + lane) * 8));
    afr2[s] = *(const bf16x8*)(w2 + (size_t)((s * 64 + lane) * 8));
  }

  const int px_l = lane & 15;
  const int og = lane >> 4;

  f32x4 acc1[8], acc2[8];
  {
    f32x4 bv1, bv2;
#pragma unroll
    for (int r = 0; r < 4; ++r) {
      bv1[r] = b1[og * 4 + r];
      bv2[r] = b2[og * 4 + r];
    }
#pragma unroll
    for (int t = 0; t < 8; ++t) { acc1[t] = bv1; acc2[t] = bv2; }
  }

  for (int i = tid; i < PY * PX * NSLOT; i += 256) {
    int pp = i / NSLOT;
    int s = i - pp * NSLOT;
    int ly = pp / PX;
    int lx = pp - ly * PX;
    int gy = ty0 + ly - 1;
    int gx = tx0 + lx - 1;
    uint4 v = make_uint4(0, 0, 0, 0);
    if (gy >= 0 && gy < HH && gx >= 0 && gx < WW) {
      const unsigned short* src = (s < 2) ? inA : inB;
      int sl = (s >= 2) ? s - 2 : s;
      v = *(const uint4*)(src + ((size_t)b * HWW + (size_t)gy * WW + gx) * 16 + sl * 8);
    }
    int swz = (s ^ (pp >> SHIFT)) & 3;
    *(uint4*)(smem + (size_t)pp * STRIDE + (swz << 4)) = v;
  }
  __syncthreads();

  int dpix[NST], dslot[NST];
#pragma unroll
  for (int s = 0; s < NST; ++s) {
    int klin = s * 32 + og * 8;
    int tap = klin / 32;
    int coff = klin % 32;
    dpix[s] = (tap / 3) * PX + (tap % 3);
    dslot[s] = coff >> 3;
  }

  const int oy_l = wv * 2;
#pragma unroll
  for (int t = 0; t < 8; ++t) {
    const int base_pix = (oy_l + (t >> 2)) * PX + (t & 3) * 16 + px_l;
#pragma unroll
    for (int s = 0; s < NST; ++s) {
      int pp = base_pix + dpix[s];
      int off = pp * STRIDE + (((dslot[s] ^ (pp >> SHIFT)) & 3) << 4);
      bf16x8 bvv = *(const bf16x8*)(smem + off);
      acc1[t] = __builtin_amdgcn_mfma_f32_16x16x32_bf16(afr1[s], bvv, acc1[t], 0, 0, 0);
      acc2[t] = __builtin_amdgcn_mfma_f32_16x16x32_bf16(afr2[s], bvv, acc2[t], 0, 0, 0);
    }
  }

#pragma unroll
  for (int t = 0; t < 8; ++t) {
    const int gy = ty0 + oy_l + (t >> 2);
    const int gx = tx0 + (t & 3) * 16 + px_l;
    const int o0 = og * 4;
    size_t base = ((size_t)b * HWW + (size_t)gy * WW + gx) * 16 + o0;
    {
      unsigned lo = (unsigned)f2bf(fmaxf(acc1[t][0], 0.f)) |
                    ((unsigned)f2bf(fmaxf(acc1[t][1], 0.f)) << 16);
      unsigned hi = (unsigned)f2bf(fmaxf(acc1[t][2], 0.f)) |
                    ((unsigned)f2bf(fmaxf(acc1[t][3], 0.f)) << 16);
      *(uint2*)(out1 + base) = make_uint2(lo, hi);
    }
    {
      unsigned lo = (unsigned)f2bf(fmaxf(acc2[t][0], 0.f)) |
                    ((unsigned)f2bf(fmaxf(acc2[t][1], 0.f)) << 16);
      unsigned hi = (unsigned)f2bf(fmaxf(acc2[t][2], 0.f)) |
                    ((unsigned)f2bf(fmaxf(acc2[t][3], 0.f)) << 16);
      *(uint2*)(out2 + base) = make_uint2(lo, hi);
    }
  }
}

// ---------------------------------------------------------------------------
// Fused K2+K3 (sagate): per halo pixel compute M = sigmoid(conv1(conv_a))
// from global conv_a taps, f_Esa = XE*M written straight into the LDS B-tile
// (slots 0,1); f_F staged into slots 2,3; then standard CIN=32 MFMA conv
// with ref_w -> f_EFsa (bf16 NHWC + ReLU).
// ---------------------------------------------------------------------------
__global__ __launch_bounds__(256) void sagate_k(
    const unsigned short* __restrict__ xa, const unsigned short* __restrict__ xe,
    const unsigned short* __restrict__ xf,
    const float* __restrict__ gw, const float* __restrict__ gb,
    const unsigned short* __restrict__ wtm, const float* __restrict__ bias,
    unsigned short* __restrict__ out) {
  constexpr int NSLOT = 4, NST = 9, SHIFT = 1, STRIDE = 64, PX = 66, PY = 10;
  __shared__ __align__(16) char smem[PY * PX * STRIDE];

  const int b = blockIdx.z;
  const int tx0 = blockIdx.x * 64;
  const int ty0 = blockIdx.y * 8;
  const int tid = threadIdx.x;
  const int lane = tid & 63;
  const int wv = tid >> 6;

  bf16x8 afr[NST];
#pragma unroll
  for (int s = 0; s < NST; ++s)
    afr[s] = *(const bf16x8*)(wtm + (size_t)((s * 64 + lane) * 8));

  const int px_l = lane & 15;
  const int og = lane >> 4;

  f32x4 acc[8];
  {
    f32x4 bv;
#pragma unroll
    for (int r = 0; r < 4; ++r) bv[r] = bias[og * 4 + r];
#pragma unroll
    for (int t = 0; t < 8; ++t) acc[t] = bv;
  }

  // stage f_F into slots 2,3
  for (int i = tid; i < PY * PX * 2; i += 256) {
    int pp = i >> 1;
    int s = 2 + (i & 1);
    int ly = pp / PX;
    int lx = pp - ly * PX;
    int gy = ty0 + ly - 1;
    int gx = tx0 + lx - 1;
    uint4 v = make_uint4(0, 0, 0, 0);
    if (gy >= 0 && gy < HH && gx >= 0 && gx < WW)
      v = *(const uint4*)(xf + ((size_t)b * HWW + (size_t)gy * WW + gx) * 16 + (s - 2) * 8);
    int swz = (s ^ (pp >> SHIFT)) & 3;
    *(uint4*)(smem + (size_t)pp * STRIDE + (swz << 4)) = v;
  }

  // gate conv + f_Esa into slots 0,1
  const float gbias = gb[0];
  for (int i = tid; i < PY * PX; i += 256) {
    int ly = i / PX;
    int lx = i - ly * PX;
    int gy = ty0 + ly - 1;
    int gx = tx0 + lx - 1;
    uint4 v0 = make_uint4(0, 0, 0, 0), v1 = make_uint4(0, 0, 0, 0);
    if (gy >= 0 && gy < HH && gx >= 0 && gx < WW) {
      float a = gbias;
#pragma unroll
      for (int ky = 0; ky < 3; ++ky) {
        int ay = gy + ky - 1;
        if (ay < 0 || ay >= HH) continue;
#pragma unroll
        for (int kx = 0; kx < 3; ++kx) {
          int ax = gx + kx - 1;
          if (ax < 0 || ax >= WW) continue;
          const int k = ky * 3 + kx;
          const uint4* p = (const uint4*)(xa + ((size_t)b * HWW + (size_t)ay * WW + ax) * 16);
          uint4 t0 = p[0], t1 = p[1];
          unsigned wv8[8] = {t0.x, t0.y, t0.z, t0.w, t1.x, t1.y, t1.z, t1.w};
#pragma unroll
          for (int j = 0; j < 8; ++j) {
            a = fmaf(bf_lo(wv8[j]), gw[(2 * j) * 9 + k], a);
            a = fmaf(bf_hi(wv8[j]), gw[(2 * j + 1) * 9 + k], a);
          }
        }
      }
      float m = 1.0f / (1.0f + expf(-a));
      const uint4* pe = (const uint4*)(xe + ((size_t)b * HWW + (size_t)gy * WW + gx) * 16);
      uint4 e0 = pe[0], e1 = pe[1];
      unsigned ev[8] = {e0.x, e0.y, e0.z, e0.w, e1.x, e1.y, e1.z, e1.w};
      unsigned r[8];
#pragma unroll
      for (int j = 0; j < 8; ++j) {
        unsigned short lo = f2bf(bf_lo(ev[j]) * m);
        unsigned short hi = f2bf(bf_hi(ev[j]) * m);
        r[j] = (unsigned)lo | ((unsigned)hi << 16);
      }
      v0 = make_uint4(r[0], r[1], r[2], r[3]);
      v1 = make_uint4(r[4], r[5], r[6], r[7]);
    }
    int swz0 = (0 ^ (i >> SHIFT)) & 3;
    int swz1 = (1 ^ (i >> SHIFT)) & 3;
    *(uint4*)(smem + (size_t)i * STRIDE + (swz0 << 4)) = v0;
    *(uint4*)(smem + (size_t)i * STRIDE + (swz1 << 4)) = v1;
  }
  __syncthreads();

  int dpix[NST], dslot[NST];
#pragma unroll
  for (int s = 0; s < NST; ++s) {
    int klin = s * 32 + og * 8;
    int tap = klin / 32;
    int coff = klin % 32;
    dpix[s] = (tap / 3) * PX + (tap % 3);
    dslot[s] = coff >> 3;
  }

  const int oy_l = wv * 2;
#pragma unroll
  for (int t = 0; t < 8; ++t) {
    const int base_pix = (oy_l + (t >> 2)) * PX + (t & 3) * 16 + px_l;
#pragma unroll
    for (int s = 0; s < NST; ++s) {
      int pp = base_pix + dpix[s];
      int off = pp * STRIDE + (((dslot[s] ^ (pp >> SHIFT)) & 3) << 4);
      bf16x8 bvv = *(const bf16x8*)(smem + off);
      acc[t] = __builtin_amdgcn_mfma_f32_16x16x32_bf16(afr[s], bvv, acc[t], 0, 0, 0);
    }
  }

#pragma unroll
  for (int t = 0; t < 8; ++t) {
    const int gy = ty0 + oy_l + (t >> 2);
    const int gx = tx0 + (t & 3) * 16 + px_l;
    const int o0 = og * 4;
    unsigned lo = (unsigned)f2bf(fmaxf(acc[t][0], 0.f)) |
                  ((unsigned)f2bf(fmaxf(acc[t][1], 0.f)) << 16);
    unsigned hi = (unsigned)f2bf(fmaxf(acc[t][2], 0.f)) |
                  ((unsigned)f2bf(fmaxf(acc[t][3], 0.f)) << 16);
    *(uint2*)(out + ((size_t)b * HWW + (size_t)gy * WW + gx) * 16 + o0) = make_uint2(lo, hi);
  }
}

// ---------------------------------------------------------------------------
// Fused K6+K7: om = conv(om_t3, om_w3) via MFMA (raw, 27ch) -> LDS transpose
// -> modulated deformable conv per pixel -> f_Edc (bf16 NHWC + ReLU).
// ---------------------------------------------------------------------------
__global__ __launch_bounds__(256) void deform_fused_k(
    const unsigned short* __restrict__ xa, const unsigned short* __restrict__ wtm,
    const float* __restrict__ ob, const unsigned short* __restrict__ xe,
    const float* __restrict__ dwt, const float* __restrict__ db,
    unsigned short* __restrict__ out) {
  constexpr int NSLOT = 2, NST = 5, OT = 2, SHIFT = 2, STRIDE = 32, PX = 66, PY = 10;
  // union: staging (PY*PX*STRIDE = 21120 B) then om tile [8][64][36] ush = 36864 B
  __shared__ __align__(16) char smem[8 * 64 * 36 * 2];
  unsigned short* omld = (unsigned short*)smem;

  const int b = blockIdx.z;
  const int tx0 = blockIdx.x * 64;
  const int ty0 = blockIdx.y * 8;
  const int tid = threadIdx.x;
  const int lane = tid & 63;
  const int wv = tid >> 6;

  bf16x8 afr[OT][NST];
#pragma unroll
  for (int ot = 0; ot < OT; ++ot)
#pragma unroll
    for (int s = 0; s < NST; ++s)
      afr[ot][s] = *(const bf16x8*)(wtm + (size_t)(((ot * NST + s) * 64 + lane) * 8));

  const int px_l = lane & 15;
  const int og = lane >> 4;

  f32x4 acc[8][OT];
#pragma unroll
  for (int ot = 0; ot < OT; ++ot) {
    f32x4 bv;
#pragma unroll
    for (int r = 0; r < 4; ++r) {
      int o = ot * 16 + og * 4 + r;
      bv[r] = ob[o < 27 ? o : 26];
    }
#pragma unroll
    for (int t = 0; t < 8; ++t) acc[t][ot] = bv;
  }

  for (int i = tid; i < PY * PX * NSLOT; i += 256) {
    int pp = i >> 1;
    int s = i & 1;
    int ly = pp / PX;
    int lx = pp - ly * PX;
    int gy = ty0 + ly - 1;
    int gx = tx0 + lx - 1;
    uint4 v = make_uint4(0, 0, 0, 0);
    if (gy >= 0 && gy < HH && gx >= 0 && gx < WW)
      v = *(const uint4*)(xa + ((size_t)b * HWW + (size_t)gy * WW + gx) * 16 + s * 8);
    int swz = (s ^ (pp >> SHIFT)) & 1;
    *(uint4*)(smem + (size_t)pp * STRIDE + (swz << 4)) = v;
  }
  __syncthreads();

  int dpix[NST], dslot[NST];
#pragma unroll
  for (int s = 0; s < NST; ++s) {
    int klin = s * 32 + og * 8;
    int tap = klin / 16;
    if (tap > 8) tap = 8;
    int coff = klin % 16;
    dpix[s] = (tap / 3) * PX + (tap % 3);
    dslot[s] = coff >> 3;
  }

  const int oy_l = wv * 2;
#pragma unroll
  for (int t = 0; t < 8; ++t) {
    const int base_pix = (oy_l + (t >> 2)) * PX + (t & 3) * 16 + px_l;
#pragma unroll
    for (int s = 0; s < NST; ++s) {
      int pp = base_pix + dpix[s];
      int off = pp * STRIDE + (((dslot[s] ^ (pp >> SHIFT)) & 1) << 4);
      bf16x8 bvv = *(const bf16x8*)(smem + off);
#pragma unroll
      for (int ot = 0; ot < OT; ++ot)
        acc[t][ot] = __builtin_amdgcn_mfma_f32_16x16x32_bf16(afr[ot][s], bvv, acc[t][ot], 0, 0, 0);
    }
  }
  __syncthreads();   // all waves done reading staging before om overwrite

#pragma unroll
  for (int t = 0; t < 8; ++t) {
    const int pyl = oy_l + (t >> 2);
    const int pxl = (t & 3) * 16 + px_l;
#pragma unroll
    for (int ot = 0; ot < OT; ++ot) {
      const int o0 = ot * 16 + og * 4;
      unsigned lo = (unsigned)f2bf(acc[t][ot][0]) | ((unsigned)f2bf(acc[t][ot][1]) << 16);
      unsigned hi = (unsigned)f2bf(acc[t][ot][2]) | ((unsigned)f2bf(acc[t][ot][3]) << 16);
      *(uint2*)(omld + (size_t)(pyl * 64 + pxl) * 36 + o0) = make_uint2(lo, hi);
    }
  }
  __syncthreads();

  // deform: 2 pixels per thread
#pragma unroll
  for (int half = 0; half < 2; ++half) {
    const int p = tid + half * 256;
    const int pyl = p >> 6;
    const int pxl = p & 63;
    const int gy = ty0 + pyl;
    const int gx = tx0 + pxl;
    const unsigned short* omp = omld + (size_t)(pyl * 64 + pxl) * 36;
    const unsigned short* xb = xe + (size_t)b * HWW * 16;

    float acc2[16];
#pragma unroll
    for (int o = 0; o < 16; ++o) acc2[o] = db[o];

#pragma unroll
    for (int k = 0; k < 9; ++k) {
      float offy = bf2f(omp[2 * k]);
      float offx = bf2f(omp[2 * k + 1]);
      float m = 1.0f / (1.0f + expf(-bf2f(omp[18 + k])));
      float py = (float)gy + (float)(k / 3 - 1) + offy;
      float px = (float)gx + (float)(k % 3 - 1) + offx;
      float y0f = floorf(py);
      float x0f = floorf(px);
      float dy = py - y0f;
      float dx = px - x0f;
      int y0 = (int)y0f, x0 = (int)x0f;
      int y1 = y0 + 1, x1 = x0 + 1;
      bool vy0 = (y0 >= 0) && (y0 < HH);
      bool vy1 = (y1 >= 0) && (y1 < HH);
      bool vx0 = (x0 >= 0) && (x0 < WW);
      bool vx1 = (x1 >= 0) && (x1 < WW);
      int yc0 = min(max(y0, 0), HH - 1);
      int yc1 = min(max(y1, 0), HH - 1);
      int xc0 = min(max(x0, 0), WW - 1);
      int xc1 = min(max(x1, 0), WW - 1);
      float w00 = (1.f - dy) * (1.f - dx) * m;
      float w01 = (1.f - dy) * dx * m;
      float w10 = dy * (1.f - dx) * m;
      float w11 = dy * dx * m;
      if (!(vy0 && vx0)) w00 = 0.f;
      if (!(vy0 && vx1)) w01 = 0.f;
      if (!(vy1 && vx0)) w10 = 0.f;
      if (!(vy1 && vx1)) w11 = 0.f;

      const uint4* p00 = (const uint4*)(xb + (size_t)(yc0 * WW + xc0) * 16);
      const uint4* p01 = (const uint4*)(xb + (size_t)(yc0 * WW + xc1) * 16);
      const uint4* p10 = (const uint4*)(xb + (size_t)(yc1 * WW + xc0) * 16);
      const uint4* p11 = (const uint4*)(xb + (size_t)(yc1 * WW + xc1) * 16);
      uint4 a0 = p00[0], a1 = p00[1];
      uint4 b0 = p01[0], b1 = p01[1];
      uint4 c0 = p10[0], c1 = p10[1];
      uint4 d0 = p11[0], d1 = p11[1];
      unsigned wA[8] = {a0.x, a0.y, a0.z, a0.w, a1.x, a1.y, a1.z, a1.w};
      unsigned wB[8] = {b0.x, b0.y, b0.z, b0.w, b1.x, b1.y, b1.z, b1.w};
      unsigned wC[8] = {c0.x, c0.y, c0.z, c0.w, c1.x, c1.y, c1.z, c1.w};
      unsigned wD[8] = {d0.x, d0.y, d0.z, d0.w, d1.x, d1.y, d1.z, d1.w};

      float sv[16];
#pragma unroll
      for (int j = 0; j < 8; ++j) {
        sv[2 * j]     = bf_lo(wA[j]) * w00 + bf_lo(wB[j]) * w01 + bf_lo(wC[j]) * w10 + bf_lo(wD[j]) * w11;
        sv[2 * j + 1] = bf_hi(wA[j]) * w00 + bf_hi(wB[j]) * w01 + bf_hi(wC[j]) * w10 + bf_hi(wD[j]) * w11;
      }
      const float* wk = dwt + (size_t)k * 256;
#pragma unroll
      for (int c = 0; c < 16; ++c)
#pragma unroll
        for (int o = 0; o < 16; ++o)
          acc2[o] = fmaf(sv[c], wk[c * 16 + o], acc2[o]);
    }
    unsigned r[8];
#pragma unroll
    for (int j = 0; j < 8; ++j) {
      unsigned short lo = f2bf(fmaxf(acc2[2 * j], 0.f));
      unsigned short hi = f2bf(fmaxf(acc2[2 * j + 1], 0.f));
      r[j] = (unsigned)lo | ((unsigned)hi << 16);
    }
    uint4* d4 = (uint4*)(out + ((size_t)b * HWW + (size_t)gy * WW + gx) * 16);
    d4[0] = make_uint4(r[0], r[1], r[2], r[3]);
    d4[1] = make_uint4(r[4], r[5], r[6], r[7]);
  }
}

extern "C" void kernel_launch(void* const* d_in, const int* in_sizes, int n_in,
                              void* d_out, int out_size, void* d_ws, size_t ws_size,
                              hipStream_t stream) {
  (void)in_sizes; (void)n_in; (void)out_size; (void)ws_size;
  const float* f_E = (const float*)d_in[0];
  const float* f_F = (const float*)d_in[1];
  const float* att_w1 = (const float*)d_in[2];
  const float* att_b1 = (const float*)d_in[3];
  const float* att_w2 = (const float*)d_in[4];
  const float* att_b2 = (const float*)d_in[5];
  const float* ref_w = (const float*)d_in[6];
  const float* ref_b = (const float*)d_in[7];
  const float* om_w1 = (const float*)d_in[8];
  const float* om_b1 = (const float*)d_in[9];
  const float* om_w2 = (const float*)d_in[10];
  const float* om_b2 = (const float*)d_in[11];
  const float* om_w3 = (const float*)d_in[12];
  const float* om_b3 = (const float*)d_in[13];
  const float* dcb_w = (const float*)d_in[14];
  const float* dcb_b = (const float*)d_in[15];
  const float* dcbref_w = (const float*)d_in[16];
  const float* dcbref_b = (const float*)d_in[17];
  const float* fin_w = (const float*)d_in[18];
  const float* fin_b = (const float*)d_in[19];
  float* outp = (float*)d_out;

  const size_t TN = (size_t)4 * HWW * 16;            // bf16 NHWC tensor elems
  unsigned short* XE  = (unsigned short*)d_ws;       // f_E
  unsigned short* XF  = XE + TN;                     // f_F
  unsigned short* XA  = XF + TN;                     // conv_a -> om_t3
  unsigned short* XT  = XA + TN;                     // om_t2 -> f_EFdc
  unsigned short* X2  = XT + TN;                     // f_EFsa
  unsigned short* XSA = X2 + TN;                     // f_Edc
  unsigned short* WM  = XSA + TN;

  unsigned short* WM_att1 = WM;                 // CIN32 OT1: 4608 ush
  unsigned short* WM_ref  = WM_att1 + 4608;
  unsigned short* WM_om1  = WM_ref + 4608;
  unsigned short* WM_om2  = WM_om1 + 4608;      // CIN16 OT1: 2560
  unsigned short* WM_om3  = WM_om2 + 2560;      // CIN16 OT2: 5120
  unsigned short* WM_dref = WM_om3 + 5120;
  unsigned short* WM_fin  = WM_dref + 4608;
  float* WF_att2 = (float*)(WM_fin + 4608);     // mode0: 144 f
  float* WF_dcb  = WF_att2 + 144;               // mode1: 2304 f

  RA ra;
  ra.d[0] = {att_w1, WM_att1, 32, 16, 2};
  ra.d[1] = {ref_w, WM_ref, 32, 16, 2};
  ra.d[2] = {om_w1, WM_om1, 32, 16, 2};
  ra.d[3] = {om_w2, WM_om2, 16, 16, 2};
  ra.d[4] = {om_w3, WM_om3, 16, 27, 2};
  ra.d[5] = {dcbref_w, WM_dref, 32, 16, 2};
  ra.d[6] = {fin_w, WM_fin, 32, 16, 2};
  ra.d[7] = {att_w2, WF_att2, 16, 1, 0};
  ra.d[8] = {dcb_w, WF_dcb, 16, 16, 1};
  repack_k<<<dim3(9), dim3(256), 0, stream>>>(ra);
  nhwc2_k<<<dim3(HWW / 256, 1, 4), dim3(256), 0, stream>>>(f_E, f_F, XE, XF);

  dim3 blk(256);
  dim3 gm(WW / 64, HH / 8, 4);   // 4 x 32 x 4 = 512 blocks

  // K1+K4: conv_a, om_t2
  conv_dual_k<<<gm, blk, 0, stream>>>(XE, XF, WM_att1, att_b1, WM_om1, om_b1, XA, XT);
  // K2+K3: f_EFsa
  sagate_k<<<gm, blk, 0, stream>>>(XA, XE, XF, WF_att2, att_b2, WM_ref, ref_b, X2);
  // K5: om_t3 (XA reused)
  conv_nhwc<2, 1, 2, 16><<<gm, blk, 0, stream>>>(XT, nullptr, WM_om2, om_b2, XA);
  // K6+K7: f_Edc
  deform_fused_k<<<gm, blk, 0, stream>>>(XA, WM_om3, om_b3, XE, WF_dcb, dcb_b, XSA);
  // K8: f_EFdc (XT reused)
  conv_nhwc<4, 1, 2, 16><<<gm, blk, 0, stream>>>(XSA, XF, WM_dref, dcbref_b, XT);
  // K9: out (fp32 NCHW)
  conv_nhwc<4, 1, 0, 16><<<gm, blk, 0, stream>>>(X2, XT, WM_fin, fin_b, outp);
}

// Round 6
// 121.778 us; speedup vs baseline: 2.5955x; 2.5955x over previous
//
#include <hip/hip_runtime.h>
#include <cstdint>
#include <cstddef>

#define HH 256
#define WW 256
#define HWW (HH * WW)

typedef __attribute__((ext_vector_type(8))) short bf16x8;
typedef __attribute__((ext_vector_type(4))) float f32x4;

__device__ inline unsigned short f2bf(float f) {
  unsigned u = __float_as_uint(f);
  unsigned r = (u + 0x7fffu + ((u >> 16) & 1u)) >> 16;
  return (unsigned short)r;
}
__device__ inline float bf2f(unsigned short u) {
  return __uint_as_float((unsigned)u << 16);
}
__device__ inline float bf_lo(unsigned w) { return __uint_as_float(w << 16); }
__device__ inline float bf_hi(unsigned w) { return __uint_as_float(w & 0xffff0000u); }

// ---------------------------------------------------------------------------
// Weight repack.
// mode 0: [cin][9] fp32 (cout==1 gate conv)
// mode 1: [k][cin][cout] fp32 (deform)
// mode 2: MFMA A-fragment pack (weights = A operand), bf16.
// ---------------------------------------------------------------------------
struct RD { const float* src; void* dst; int cin, cout, mode; };
struct RA { RD d[9]; };

__global__ __launch_bounds__(256) void repack_k(RA a) {
  const RD t = a.d[blockIdx.x];
  if (t.mode == 2) {
    const int NST = (t.cin * 9 + 31) / 32;
    const int OT = (t.cout + 15) / 16;
    const int n = OT * NST * 512;
    unsigned short* dst = (unsigned short*)t.dst;
    for (int i = threadIdx.x; i < n; i += 256) {
      int j = i & 7;
      int l = (i >> 3) & 63;
      int rest = i >> 9;
      int s = rest % NST;
      int ot = rest / NST;
      int o = ot * 16 + (l & 15);
      int klin = s * 32 + ((l >> 4) << 3) + j;
      int tap = klin / t.cin;
      int c = klin % t.cin;
      float v = 0.f;
      if (tap < 9 && o < t.cout) v = t.src[(o * t.cin + c) * 9 + tap];
      dst[i] = f2bf(v);
    }
  } else {
    float* dst = (float*)t.dst;
    const int n = t.cin * t.cout * 9;
    for (int i = threadIdx.x; i < n; i += 256) {
      int k = i % 9;
      int rest = i / 9;
      int c = rest % t.cin;
      int o = rest / t.cin;
      if (t.mode == 0) dst[(c * 9 + k) * t.cout + o] = t.src[(o * t.cin + c) * 9 + k];
      else             dst[(k * t.cin + c) * t.cout + o] = t.src[(o * t.cin + c) * 9 + k];
    }
  }
}

// ---------------------------------------------------------------------------
// f_E, f_F (fp32 NCHW) -> bf16 NHWC [B][H][W][16].
// ---------------------------------------------------------------------------
__global__ __launch_bounds__(256) void nhwc2_k(
    const float* __restrict__ fe, const float* __restrict__ ff,
    unsigned short* __restrict__ xe, unsigned short* __restrict__ xf) {
  const int b = blockIdx.z;
  const int pixel = blockIdx.x * 256 + threadIdx.x;
#pragma unroll
  for (int t = 0; t < 2; ++t) {
    const float* src = t ? ff : fe;
    unsigned short* dst = t ? xf : xe;
    unsigned w[8];
#pragma unroll
    for (int j = 0; j < 8; ++j) {
      unsigned short lo = f2bf(src[((size_t)b * 16 + 2 * j) * HWW + pixel]);
      unsigned short hi = f2bf(src[((size_t)b * 16 + 2 * j + 1) * HWW + pixel]);
      w[j] = (unsigned)lo | ((unsigned)hi << 16);
    }
    uint4* d4 = (uint4*)(dst + ((size_t)b * HWW + pixel) * 16);
    d4[0] = make_uint4(w[0], w[1], w[2], w[3]);
    d4[1] = make_uint4(w[4], w[5], w[6], w[7]);
  }
}

// ---------------------------------------------------------------------------
// Generic single-conv. OUT_MODE 0: fp32 NCHW + ReLU. 1: bf16 NCHW planes raw.
// 2: bf16 NHWC + ReLU.
// ---------------------------------------------------------------------------
template <int NSLOT, int OT, int OUT_MODE, int COUTR>
__global__ __launch_bounds__(256) void conv_nhwc(
    const unsigned short* __restrict__ inA, const unsigned short* __restrict__ inB,
    const unsigned short* __restrict__ wtm, const float* __restrict__ bias,
    void* __restrict__ outv) {
  constexpr int CIN = NSLOT * 8;
  constexpr int NST = (CIN * 9 + 31) / 32;
  constexpr int SHIFT = (NSLOT == 4) ? 1 : 2;
  constexpr int STRIDE = NSLOT * 16;
  constexpr int PX = 66, PY = 10;
  __shared__ __align__(16) char smem[PY * PX * STRIDE];

  const int b = blockIdx.z;
  const int tx0 = blockIdx.x * 64;
  const int ty0 = blockIdx.y * 8;
  const int tid = threadIdx.x;
  const int lane = tid & 63;
  const int wv = tid >> 6;

  bf16x8 afr[OT][NST];
#pragma unroll
  for (int ot = 0; ot < OT; ++ot)
#pragma unroll
    for (int s = 0; s < NST; ++s)
      afr[ot][s] = *(const bf16x8*)(wtm + (size_t)(((ot * NST + s) * 64 + lane) * 8));

  const int px_l = lane & 15;
  const int og = lane >> 4;

  f32x4 acc[8][OT];
#pragma unroll
  for (int ot = 0; ot < OT; ++ot) {
    f32x4 bv;
#pragma unroll
    for (int r = 0; r < 4; ++r) {
      int o = ot * 16 + og * 4 + r;
      bv[r] = bias[o < COUTR ? o : COUTR - 1];
    }
#pragma unroll
    for (int t = 0; t < 8; ++t) acc[t][ot] = bv;
  }

  for (int i = tid; i < PY * PX * NSLOT; i += 256) {
    int pp = i / NSLOT;
    int s = i - pp * NSLOT;
    int ly = pp / PX;
    int lx = pp - ly * PX;
    int gy = ty0 + ly - 1;
    int gx = tx0 + lx - 1;
    uint4 v = make_uint4(0, 0, 0, 0);
    if (gy >= 0 && gy < HH && gx >= 0 && gx < WW) {
      const unsigned short* src = (NSLOT == 2 || s < 2) ? inA : inB;
      int sl = (NSLOT == 4 && s >= 2) ? s - 2 : s;
      v = *(const uint4*)(src + ((size_t)b * HWW + (size_t)gy * WW + gx) * 16 + sl * 8);
    }
    int swz = (s ^ (pp >> SHIFT)) & (NSLOT - 1);
    *(uint4*)(smem + (size_t)pp * STRIDE + (swz << 4)) = v;
  }
  __syncthreads();

  int dpix[NST], dslot[NST];
#pragma unroll
  for (int s = 0; s < NST; ++s) {
    int klin = s * 32 + og * 8;
    int tap = klin / CIN;
    if (tap > 8) tap = 8;
    int coff = klin % CIN;
    dpix[s] = (tap / 3) * PX + (tap % 3);
    dslot[s] = coff >> 3;
  }

  const int oy_l = wv * 2;
#pragma unroll
  for (int t = 0; t < 8; ++t) {
    const int base_pix = (oy_l + (t >> 2)) * PX + (t & 3) * 16 + px_l;
#pragma unroll
    for (int s = 0; s < NST; ++s) {
      int pp = base_pix + dpix[s];
      int off = pp * STRIDE + (((dslot[s] ^ (pp >> SHIFT)) & (NSLOT - 1)) << 4);
      bf16x8 bvv = *(const bf16x8*)(smem + off);
#pragma unroll
      for (int ot = 0; ot < OT; ++ot)
        acc[t][ot] = __builtin_amdgcn_mfma_f32_16x16x32_bf16(afr[ot][s], bvv, acc[t][ot], 0, 0, 0);
    }
  }

#pragma unroll
  for (int t = 0; t < 8; ++t) {
    const int gy = ty0 + oy_l + (t >> 2);
    const int gx = tx0 + (t & 3) * 16 + px_l;
#pragma unroll
    for (int ot = 0; ot < OT; ++ot) {
      const int o0 = ot * 16 + og * 4;
      if (OUT_MODE == 2) {
        unsigned lo = (unsigned)f2bf(fmaxf(acc[t][ot][0], 0.f)) |
                      ((unsigned)f2bf(fmaxf(acc[t][ot][1], 0.f)) << 16);
        unsigned hi = (unsigned)f2bf(fmaxf(acc[t][ot][2], 0.f)) |
                      ((unsigned)f2bf(fmaxf(acc[t][ot][3], 0.f)) << 16);
        uint2* dst = (uint2*)((unsigned short*)outv +
                              ((size_t)b * HWW + (size_t)gy * WW + gx) * 16 + o0);
        *dst = make_uint2(lo, hi);
      } else if (OUT_MODE == 0) {
#pragma unroll
        for (int r = 0; r < 4; ++r) {
          int o = o0 + r;
          if (o < COUTR)
            ((float*)outv)[((size_t)b * COUTR + o) * HWW + (size_t)gy * WW + gx] =
                fmaxf(acc[t][ot][r], 0.f);
        }
      } else {
#pragma unroll
        for (int r = 0; r < 4; ++r) {
          int o = o0 + r;
          if (o < COUTR)
            ((unsigned short*)outv)[((size_t)b * COUTR + o) * HWW + (size_t)gy * WW + gx] =
                f2bf(acc[t][ot][r]);
        }
      }
    }
  }
}

// ---------------------------------------------------------------------------
// Fused K1+K4: two CIN=32 convs over one staged input cat(XE,XF).
// ---------------------------------------------------------------------------
__global__ __launch_bounds__(256) void conv_dual_k(
    const unsigned short* __restrict__ inA, const unsigned short* __restrict__ inB,
    const unsigned short* __restrict__ w1, const float* __restrict__ b1,
    const unsigned short* __restrict__ w2, const float* __restrict__ b2,
    unsigned short* __restrict__ out1, unsigned short* __restrict__ out2) {
  constexpr int NSLOT = 4, NST = 9, SHIFT = 1, STRIDE = 64, PX = 66, PY = 10;
  __shared__ __align__(16) char smem[PY * PX * STRIDE];

  const int b = blockIdx.z;
  const int tx0 = blockIdx.x * 64;
  const int ty0 = blockIdx.y * 8;
  const int tid = threadIdx.x;
  const int lane = tid & 63;
  const int wv = tid >> 6;

  bf16x8 afr1[NST], afr2[NST];
#pragma unroll
  for (int s = 0; s < NST; ++s) {
    afr1[s] = *(const bf16x8*)(w1 + (size_t)((s * 64 + lane) * 8));
    afr2[s] = *(const bf16x8*)(w2 + (size_t)((s * 64 + lane) * 8));
  }

  const int px_l = lane & 15;
  const int og = lane >> 4;

  f32x4 acc1[8], acc2[8];
  {
    f32x4 bv1, bv2;
#pragma unroll
    for (int r = 0; r < 4; ++r) {
      bv1[r] = b1[og * 4 + r];
      bv2[r] = b2[og * 4 + r];
    }
#pragma unroll
    for (int t = 0; t < 8; ++t) { acc1[t] = bv1; acc2[t] = bv2; }
  }

  for (int i = tid; i < PY * PX * NSLOT; i += 256) {
    int pp = i / NSLOT;
    int s = i - pp * NSLOT;
    int ly = pp / PX;
    int lx = pp - ly * PX;
    int gy = ty0 + ly - 1;
    int gx = tx0 + lx - 1;
    uint4 v = make_uint4(0, 0, 0, 0);
    if (gy >= 0 && gy < HH && gx >= 0 && gx < WW) {
      const unsigned short* src = (s < 2) ? inA : inB;
      int sl = (s >= 2) ? s - 2 : s;
      v = *(const uint4*)(src + ((size_t)b * HWW + (size_t)gy * WW + gx) * 16 + sl * 8);
    }
    int swz = (s ^ (pp >> SHIFT)) & 3;
    *(uint4*)(smem + (size_t)pp * STRIDE + (swz << 4)) = v;
  }
  __syncthreads();

  int dpix[NST], dslot[NST];
#pragma unroll
  for (int s = 0; s < NST; ++s) {
    int klin = s * 32 + og * 8;
    int tap = klin / 32;
    int coff = klin % 32;
    dpix[s] = (tap / 3) * PX + (tap % 3);
    dslot[s] = coff >> 3;
  }

  const int oy_l = wv * 2;
#pragma unroll
  for (int t = 0; t < 8; ++t) {
    const int base_pix = (oy_l + (t >> 2)) * PX + (t & 3) * 16 + px_l;
#pragma unroll
    for (int s = 0; s < NST; ++s) {
      int pp = base_pix + dpix[s];
      int off = pp * STRIDE + (((dslot[s] ^ (pp >> SHIFT)) & 3) << 4);
      bf16x8 bvv = *(const bf16x8*)(smem + off);
      acc1[t] = __builtin_amdgcn_mfma_f32_16x16x32_bf16(afr1[s], bvv, acc1[t], 0, 0, 0);
      acc2[t] = __builtin_amdgcn_mfma_f32_16x16x32_bf16(afr2[s], bvv, acc2[t], 0, 0, 0);
    }
  }

#pragma unroll
  for (int t = 0; t < 8; ++t) {
    const int gy = ty0 + oy_l + (t >> 2);
    const int gx = tx0 + (t & 3) * 16 + px_l;
    const int o0 = og * 4;
    size_t base = ((size_t)b * HWW + (size_t)gy * WW + gx) * 16 + o0;
    {
      unsigned lo = (unsigned)f2bf(fmaxf(acc1[t][0], 0.f)) |
                    ((unsigned)f2bf(fmaxf(acc1[t][1], 0.f)) << 16);
      unsigned hi = (unsigned)f2bf(fmaxf(acc1[t][2], 0.f)) |
                    ((unsigned)f2bf(fmaxf(acc1[t][3], 0.f)) << 16);
      *(uint2*)(out1 + base) = make_uint2(lo, hi);
    }
    {
      unsigned lo = (unsigned)f2bf(fmaxf(acc2[t][0], 0.f)) |
                    ((unsigned)f2bf(fmaxf(acc2[t][1], 0.f)) << 16);
      unsigned hi = (unsigned)f2bf(fmaxf(acc2[t][2], 0.f)) |
                    ((unsigned)f2bf(fmaxf(acc2[t][3], 0.f)) << 16);
      *(uint2*)(out2 + base) = make_uint2(lo, hi);
    }
  }
}

// ---------------------------------------------------------------------------
// Fused K2+K3 (sagate): gate conv + f_Esa straight into the LDS B-tile,
// then CIN=32 MFMA conv with ref_w -> f_EFsa.
// ---------------------------------------------------------------------------
__global__ __launch_bounds__(256) void sagate_k(
    const unsigned short* __restrict__ xa, const unsigned short* __restrict__ xe,
    const unsigned short* __restrict__ xf,
    const float* __restrict__ gw, const float* __restrict__ gb,
    const unsigned short* __restrict__ wtm, const float* __restrict__ bias,
    unsigned short* __restrict__ out) {
  constexpr int NST = 9, SHIFT = 1, STRIDE = 64, PX = 66, PY = 10;
  __shared__ __align__(16) char smem[PY * PX * STRIDE];

  const int b = blockIdx.z;
  const int tx0 = blockIdx.x * 64;
  const int ty0 = blockIdx.y * 8;
  const int tid = threadIdx.x;
  const int lane = tid & 63;
  const int wv = tid >> 6;

  bf16x8 afr[NST];
#pragma unroll
  for (int s = 0; s < NST; ++s)
    afr[s] = *(const bf16x8*)(wtm + (size_t)((s * 64 + lane) * 8));

  const int px_l = lane & 15;
  const int og = lane >> 4;

  f32x4 acc[8];
  {
    f32x4 bv;
#pragma unroll
    for (int r = 0; r < 4; ++r) bv[r] = bias[og * 4 + r];
#pragma unroll
    for (int t = 0; t < 8; ++t) acc[t] = bv;
  }

  for (int i = tid; i < PY * PX * 2; i += 256) {
    int pp = i >> 1;
    int s = 2 + (i & 1);
    int ly = pp / PX;
    int lx = pp - ly * PX;
    int gy = ty0 + ly - 1;
    int gx = tx0 + lx - 1;
    uint4 v = make_uint4(0, 0, 0, 0);
    if (gy >= 0 && gy < HH && gx >= 0 && gx < WW)
      v = *(const uint4*)(xf + ((size_t)b * HWW + (size_t)gy * WW + gx) * 16 + (s - 2) * 8);
    int swz = (s ^ (pp >> SHIFT)) & 3;
    *(uint4*)(smem + (size_t)pp * STRIDE + (swz << 4)) = v;
  }

  const float gbias = gb[0];
  for (int i = tid; i < PY * PX; i += 256) {
    int ly = i / PX;
    int lx = i - ly * PX;
    int gy = ty0 + ly - 1;
    int gx = tx0 + lx - 1;
    uint4 v0 = make_uint4(0, 0, 0, 0), v1 = make_uint4(0, 0, 0, 0);
    if (gy >= 0 && gy < HH && gx >= 0 && gx < WW) {
      float a = gbias;
#pragma unroll
      for (int ky = 0; ky < 3; ++ky) {
        int ay = gy + ky - 1;
        if (ay < 0 || ay >= HH) continue;
#pragma unroll
        for (int kx = 0; kx < 3; ++kx) {
          int ax = gx + kx - 1;
          if (ax < 0 || ax >= WW) continue;
          const int k = ky * 3 + kx;
          const uint4* p = (const uint4*)(xa + ((size_t)b * HWW + (size_t)ay * WW + ax) * 16);
          uint4 t0 = p[0], t1 = p[1];
          unsigned wv8[8] = {t0.x, t0.y, t0.z, t0.w, t1.x, t1.y, t1.z, t1.w};
#pragma unroll
          for (int j = 0; j < 8; ++j) {
            a = fmaf(bf_lo(wv8[j]), gw[(2 * j) * 9 + k], a);
            a = fmaf(bf_hi(wv8[j]), gw[(2 * j + 1) * 9 + k], a);
          }
        }
      }
      float m = 1.0f / (1.0f + expf(-a));
      const uint4* pe = (const uint4*)(xe + ((size_t)b * HWW + (size_t)gy * WW + gx) * 16);
      uint4 e0 = pe[0], e1 = pe[1];
      unsigned ev[8] = {e0.x, e0.y, e0.z, e0.w, e1.x, e1.y, e1.z, e1.w};
      unsigned r[8];
#pragma unroll
      for (int j = 0; j < 8; ++j) {
        unsigned short lo = f2bf(bf_lo(ev[j]) * m);
        unsigned short hi = f2bf(bf_hi(ev[j]) * m);
        r[j] = (unsigned)lo | ((unsigned)hi << 16);
      }
      v0 = make_uint4(r[0], r[1], r[2], r[3]);
      v1 = make_uint4(r[4], r[5], r[6], r[7]);
    }
    int swz0 = (0 ^ (i >> SHIFT)) & 3;
    int swz1 = (1 ^ (i >> SHIFT)) & 3;
    *(uint4*)(smem + (size_t)i * STRIDE + (swz0 << 4)) = v0;
    *(uint4*)(smem + (size_t)i * STRIDE + (swz1 << 4)) = v1;
  }
  __syncthreads();

  int dpix[NST], dslot[NST];
#pragma unroll
  for (int s = 0; s < NST; ++s) {
    int klin = s * 32 + og * 8;
    int tap = klin / 32;
    int coff = klin % 32;
    dpix[s] = (tap / 3) * PX + (tap % 3);
    dslot[s] = coff >> 3;
  }

  const int oy_l = wv * 2;
#pragma unroll
  for (int t = 0; t < 8; ++t) {
    const int base_pix = (oy_l + (t >> 2)) * PX + (t & 3) * 16 + px_l;
#pragma unroll
    for (int s = 0; s < NST; ++s) {
      int pp = base_pix + dpix[s];
      int off = pp * STRIDE + (((dslot[s] ^ (pp >> SHIFT)) & 3) << 4);
      bf16x8 bvv = *(const bf16x8*)(smem + off);
      acc[t] = __builtin_amdgcn_mfma_f32_16x16x32_bf16(afr[s], bvv, acc[t], 0, 0, 0);
    }
  }

#pragma unroll
  for (int t = 0; t < 8; ++t) {
    const int gy = ty0 + oy_l + (t >> 2);
    const int gx = tx0 + (t & 3) * 16 + px_l;
    const int o0 = og * 4;
    unsigned lo = (unsigned)f2bf(fmaxf(acc[t][0], 0.f)) |
                  ((unsigned)f2bf(fmaxf(acc[t][1], 0.f)) << 16);
    unsigned hi = (unsigned)f2bf(fmaxf(acc[t][2], 0.f)) |
                  ((unsigned)f2bf(fmaxf(acc[t][3], 0.f)) << 16);
    *(uint2*)(out + ((size_t)b * HWW + (size_t)gy * WW + gx) * 16 + o0) = make_uint2(lo, hi);
  }
}

// ---------------------------------------------------------------------------
// Modulated deformable conv 3x3, 16->16, + ReLU. Standalone (low VGPR, high
// occupancy). x: bf16 NHWC; om: bf16 NCHW planes; weights [k][c][o] fp32.
// Output bf16 NHWC. XCD-aware: batch b pinned to XCDs {2b,2b+1}.
// ---------------------------------------------------------------------------
__global__ __launch_bounds__(256) void deform_v4(
    const unsigned short* __restrict__ xn, const unsigned short* __restrict__ om,
    const float* __restrict__ wt, const float* __restrict__ bias,
    unsigned short* __restrict__ out) {
  const int bid = blockIdx.x;
  const int xcd = bid & 7;
  const int b = xcd >> 1;
  const int pb = ((bid >> 3) << 1) | (xcd & 1);
  const int pixel = pb * 256 + (int)threadIdx.x;
  const int y = pixel >> 8;
  const int xq = pixel & 255;
  const unsigned short* xb = xn + (size_t)b * HWW * 16;
  const unsigned short* omb = om + (size_t)b * 27 * HWW;

  float acc[16];
#pragma unroll
  for (int o = 0; o < 16; ++o) acc[o] = bias[o];

#pragma unroll
  for (int k = 0; k < 9; ++k) {
    float offy = bf2f(omb[(size_t)(2 * k) * HWW + pixel]);
    float offx = bf2f(omb[(size_t)(2 * k + 1) * HWW + pixel]);
    float m = 1.0f / (1.0f + expf(-bf2f(omb[(size_t)(18 + k) * HWW + pixel])));
    float py = (float)y + (float)(k / 3 - 1) + offy;
    float px = (float)xq + (float)(k % 3 - 1) + offx;
    float y0f = floorf(py);
    float x0f = floorf(px);
    float dy = py - y0f;
    float dx = px - x0f;
    int y0 = (int)y0f, x0 = (int)x0f;
    int y1 = y0 + 1, x1 = x0 + 1;
    bool vy0 = (y0 >= 0) && (y0 < HH);
    bool vy1 = (y1 >= 0) && (y1 < HH);
    bool vx0 = (x0 >= 0) && (x0 < WW);
    bool vx1 = (x1 >= 0) && (x1 < WW);
    int yc0 = min(max(y0, 0), HH - 1);
    int yc1 = min(max(y1, 0), HH - 1);
    int xc0 = min(max(x0, 0), WW - 1);
    int xc1 = min(max(x1, 0), WW - 1);
    float w00 = (1.f - dy) * (1.f - dx) * m;
    float w01 = (1.f - dy) * dx * m;
    float w10 = dy * (1.f - dx) * m;
    float w11 = dy * dx * m;
    if (!(vy0 && vx0)) w00 = 0.f;
    if (!(vy0 && vx1)) w01 = 0.f;
    if (!(vy1 && vx0)) w10 = 0.f;
    if (!(vy1 && vx1)) w11 = 0.f;

    const uint4* p00 = (const uint4*)(xb + (size_t)(yc0 * WW + xc0) * 16);
    const uint4* p01 = (const uint4*)(xb + (size_t)(yc0 * WW + xc1) * 16);
    const uint4* p10 = (const uint4*)(xb + (size_t)(yc1 * WW + xc0) * 16);
    const uint4* p11 = (const uint4*)(xb + (size_t)(yc1 * WW + xc1) * 16);
    uint4 a0 = p00[0], a1 = p00[1];
    uint4 b0 = p01[0], b1 = p01[1];
    uint4 c0 = p10[0], c1 = p10[1];
    uint4 d0 = p11[0], d1 = p11[1];
    unsigned wA[8] = {a0.x, a0.y, a0.z, a0.w, a1.x, a1.y, a1.z, a1.w};
    unsigned wB[8] = {b0.x, b0.y, b0.z, b0.w, b1.x, b1.y, b1.z, b1.w};
    unsigned wC[8] = {c0.x, c0.y, c0.z, c0.w, c1.x, c1.y, c1.z, c1.w};
    unsigned wD[8] = {d0.x, d0.y, d0.z, d0.w, d1.x, d1.y, d1.z, d1.w};

    float s[16];
#pragma unroll
    for (int j = 0; j < 8; ++j) {
      s[2 * j]     = bf_lo(wA[j]) * w00 + bf_lo(wB[j]) * w01 + bf_lo(wC[j]) * w10 + bf_lo(wD[j]) * w11;
      s[2 * j + 1] = bf_hi(wA[j]) * w00 + bf_hi(wB[j]) * w01 + bf_hi(wC[j]) * w10 + bf_hi(wD[j]) * w11;
    }
    const float* wk = wt + (size_t)k * 256;
#pragma unroll
    for (int c = 0; c < 16; ++c)
#pragma unroll
      for (int o = 0; o < 16; ++o)
        acc[o] = fmaf(s[c], wk[c * 16 + o], acc[o]);
  }
  unsigned r[8];
#pragma unroll
  for (int j = 0; j < 8; ++j) {
    unsigned short lo = f2bf(fmaxf(acc[2 * j], 0.f));
    unsigned short hi = f2bf(fmaxf(acc[2 * j + 1], 0.f));
    r[j] = (unsigned)lo | ((unsigned)hi << 16);
  }
  uint4* d4 = (uint4*)(out + ((size_t)b * HWW + pixel) * 16);
  d4[0] = make_uint4(r[0], r[1], r[2], r[3]);
  d4[1] = make_uint4(r[4], r[5], r[6], r[7]);
}

extern "C" void kernel_launch(void* const* d_in, const int* in_sizes, int n_in,
                              void* d_out, int out_size, void* d_ws, size_t ws_size,
                              hipStream_t stream) {
  (void)in_sizes; (void)n_in; (void)out_size; (void)ws_size;
  const float* f_E = (const float*)d_in[0];
  const float* f_F = (const float*)d_in[1];
  const float* att_w1 = (const float*)d_in[2];
  const float* att_b1 = (const float*)d_in[3];
  const float* att_w2 = (const float*)d_in[4];
  const float* att_b2 = (const float*)d_in[5];
  const float* ref_w = (const float*)d_in[6];
  const float* ref_b = (const float*)d_in[7];
  const float* om_w1 = (const float*)d_in[8];
  const float* om_b1 = (const float*)d_in[9];
  const float* om_w2 = (const float*)d_in[10];
  const float* om_b2 = (const float*)d_in[11];
  const float* om_w3 = (const float*)d_in[12];
  const float* om_b3 = (const float*)d_in[13];
  const float* dcb_w = (const float*)d_in[14];
  const float* dcb_b = (const float*)d_in[15];
  const float* dcbref_w = (const float*)d_in[16];
  const float* dcbref_b = (const float*)d_in[17];
  const float* fin_w = (const float*)d_in[18];
  const float* fin_b = (const float*)d_in[19];
  float* outp = (float*)d_out;

  const size_t TN = (size_t)4 * HWW * 16;            // bf16 NHWC tensor elems
  unsigned short* XE  = (unsigned short*)d_ws;       // f_E
  unsigned short* XF  = XE + TN;                     // f_F
  unsigned short* XA  = XF + TN;                     // conv_a -> om_t3
  unsigned short* XT  = XA + TN;                     // om_t2 -> f_EFdc
  unsigned short* X2  = XT + TN;                     // f_EFsa
  unsigned short* XSA = X2 + TN;                     // f_Edc
  unsigned short* OMB = XSA + TN;                    // om bf16 NCHW planes
  unsigned short* WM  = OMB + (size_t)4 * 27 * HWW;

  unsigned short* WM_att1 = WM;                 // CIN32 OT1: 4608 ush
  unsigned short* WM_ref  = WM_att1 + 4608;
  unsigned short* WM_om1  = WM_ref + 4608;
  unsigned short* WM_om2  = WM_om1 + 4608;      // CIN16 OT1: 2560
  unsigned short* WM_om3  = WM_om2 + 2560;      // CIN16 OT2: 5120
  unsigned short* WM_dref = WM_om3 + 5120;
  unsigned short* WM_fin  = WM_dref + 4608;
  float* WF_att2 = (float*)(WM_fin + 4608);     // mode0: 144 f
  float* WF_dcb  = WF_att2 + 144;               // mode1: 2304 f

  RA ra;
  ra.d[0] = {att_w1, WM_att1, 32, 16, 2};
  ra.d[1] = {ref_w, WM_ref, 32, 16, 2};
  ra.d[2] = {om_w1, WM_om1, 32, 16, 2};
  ra.d[3] = {om_w2, WM_om2, 16, 16, 2};
  ra.d[4] = {om_w3, WM_om3, 16, 27, 2};
  ra.d[5] = {dcbref_w, WM_dref, 32, 16, 2};
  ra.d[6] = {fin_w, WM_fin, 32, 16, 2};
  ra.d[7] = {att_w2, WF_att2, 16, 1, 0};
  ra.d[8] = {dcb_w, WF_dcb, 16, 16, 1};
  repack_k<<<dim3(9), dim3(256), 0, stream>>>(ra);
  nhwc2_k<<<dim3(HWW / 256, 1, 4), dim3(256), 0, stream>>>(f_E, f_F, XE, XF);

  dim3 blk(256);
  dim3 gm(WW / 64, HH / 8, 4);   // 512 blocks

  // K1+K4: conv_a, om_t2
  conv_dual_k<<<gm, blk, 0, stream>>>(XE, XF, WM_att1, att_b1, WM_om1, om_b1, XA, XT);
  // K2+K3: f_EFsa
  sagate_k<<<gm, blk, 0, stream>>>(XA, XE, XF, WF_att2, att_b2, WM_ref, ref_b, X2);
  // K5: om_t3 (XA reused)
  conv_nhwc<2, 1, 2, 16><<<gm, blk, 0, stream>>>(XT, nullptr, WM_om2, om_b2, XA);
  // K6: om -> bf16 NCHW planes
  conv_nhwc<2, 2, 1, 27><<<gm, blk, 0, stream>>>(XA, nullptr, WM_om3, om_b3, OMB);
  // K7: f_Edc (standalone deform, high occupancy)
  deform_v4<<<dim3(1024), blk, 0, stream>>>(XE, OMB, WF_dcb, dcb_b, XSA);
  // K8: f_EFdc (XT reused)
  conv_nhwc<4, 1, 2, 16><<<gm, blk, 0, stream>>>(XSA, XF, WM_dref, dcbref_b, XT);
  // K9: out (fp32 NCHW)
  conv_nhwc<4, 1, 0, 16><<<gm, blk, 0, stream>>>(X2, XT, WM_fin, fin_b, outp);
}